// Round 8
// baseline (223.340 us; speedup 1.0000x reference)
//
#include <hip/hip_runtime.h>

// Fused CNN. R11: split the fused kernel into conv1_pool (A) + conv2_rest (B).
// Rationale (7 rounds of evidence): every change to the fused kernel crosses
// the 64-VGPR wave-slot cliff (R4:80, R6:72, R9:76, R10:72 -> 4 blocks/CU,
// 57-105us) because stage-1's 45-reg ring and stage-2's 28-reg acc share one
// budget; and the ~30KB overlay caps 5 blocks/CU with 8 blocks of work/CU
// (5+3 batching = the measured 34% occupancy). Splitting decouples:
//   A: no LDS, no barriers, wave=quadrant -> coalesced 128B h1t stores.
//   B: B-fragments straight from global h1t (18KB/image = L1-resident for
//      the block; 4-wave re-read is L1-hit) -> stage-2 leaves the LDS pipe;
//      LDS = cbuf bf16 [64][101] + h2t = 17088B -> 9 blocks LDS-wise.
// h1t global = 37.7MB (L3-resident; HBM at 1%). ws_size checked; exact R3
// single-kernel (proven 52us) is the fallback.

typedef __attribute__((ext_vector_type(8))) short short8;   // 8 x bf16 (4 VGPRs)
typedef __attribute__((ext_vector_type(4))) float f32x4;

__device__ inline short f2bf(float f) {   // fp32 -> bf16, round-to-nearest-even
    union { float f; unsigned u; } v; v.f = f;
    unsigned r = (v.u + 0x7FFFu + ((v.u >> 16) & 1u)) >> 16;
    return (short)r;
}
__device__ inline float bf2f(short s) {
    union { unsigned u; float f; } v; v.u = ((unsigned)(unsigned short)s) << 16;
    return v.f;
}

// w2r[s][cout][cin] (bf16), s = ky*3+kx: MFMA A-fragments contiguous in cin.
__global__ __launch_bounds__(256) void prep_w2(const float* __restrict__ w2,
                                               short* __restrict__ w2r) {
    int i = blockIdx.x * 256 + threadIdx.x;      // 9*64*64 = 36864
    if (i >= 36864) return;
    int s = i >> 12, cout = (i >> 6) & 63, cin = i & 63;
    w2r[i] = f2bf(w2[cout * 576 + cin * 9 + s]);
}

// element s (0..15) of a float4[4] register row, s must be a literal
#define EL(arr, s) ((s & 3) == 0 ? arr[(s) >> 2].x : \
                    (s & 3) == 1 ? arr[(s) >> 2].y : \
                    (s & 3) == 2 ? arr[(s) >> 2].z : arr[(s) >> 2].w)

// ---------------- Kernel A: conv1 + pool 3x3 s2 + relu -> h1g ----------------
// wave = quadrant (t>>6), lane = channel (t&63). No LDS, no barriers.
// h1g[n][pos][c]: lanes write consecutive c -> one 128B store per (pos).
__global__ __launch_bounds__(256) void conv1_pool(
    const float* __restrict__ x,   // [B,1,28,28]
    const float* __restrict__ w1,  // [64,1,3,3]
    const float* __restrict__ b1,  // [64]
    short* __restrict__ h1g)       // [B,144,64] bf16
{
    const int n_img = blockIdx.x;
    const int t = threadIdx.x;
    const int c = t & 63;
    const int q = t >> 6;
    const int oy = (q >> 1) * 6, ox = (q & 1) * 6;
    const int iy0 = 2 * oy, ix0 = 2 * ox;        // ix0 in {0,12}: 16B aligned
    const float* img = x + (size_t)n_img * 784;
    short* h1o = h1g + (size_t)n_img * 9216;

    float w[9];
    #pragma unroll
    for (int k = 0; k < 9; ++k) w[k] = w1[c * 9 + k];
    const float bias = b1[c];

    float4 in0[4], in1[4], in2[4];               // ring of 3 rows, 16 floats each
    #define LOADROW4(dst, row) do { \
        const float4* p4 = (const float4*)(img + (row) * 28 + ix0); \
        dst[0] = p4[0]; dst[1] = p4[1]; dst[2] = p4[2]; dst[3] = p4[3]; } while (0)

    LOADROW4(in0, iy0 + 0);
    LOADROW4(in1, iy0 + 1);
    float cm[3][6];                              // colmax ring (3 conv rows)

    #pragma unroll
    for (int r = 0; r < 13; ++r) {               // conv rows, computed once
        LOADROW4(in2, iy0 + r + 2);
        #pragma unroll
        for (int px = 0; px < 6; ++px) cm[r % 3][px] = -1e30f;
        #pragma unroll
        for (int xx = 0; xx < 13; ++xx) {
            float a = bias;
            #pragma unroll
            for (int j = 0; j < 3; ++j) {
                a += EL(in0, xx + j) * w[j];
                a += EL(in1, xx + j) * w[3 + j];
                a += EL(in2, xx + j) * w[6 + j];
            }
            if ((xx & 1) == 0) {
                if (xx >= 2 && xx <= 12) cm[r % 3][xx / 2 - 1] = fmaxf(cm[r % 3][xx / 2 - 1], a);
                if (xx <= 10)            cm[r % 3][xx / 2]     = fmaxf(cm[r % 3][xx / 2], a);
            } else {
                cm[r % 3][xx / 2] = fmaxf(cm[r % 3][xx / 2], a);
            }
        }
        if (r >= 2 && (r & 1) == 0) {            // pooled row py = r/2 - 1 complete
            const int py = r / 2 - 1;
            #pragma unroll
            for (int px = 0; px < 6; ++px) {
                float m = fmaxf(fmaxf(cm[0][px], cm[1][px]), cm[2][px]);
                h1o[((oy + py) * 12 + ox + px) * 64 + c] = f2bf(fmaxf(m, 0.0f));
            }
        }
        #pragma unroll
        for (int i = 0; i < 4; ++i) { in0[i] = in1[i]; in1[i] = in2[i]; }
    }
    #undef LOADROW4
}

// ---------------- Kernel B: conv2 MFMA + pool + conv3 ----------------
__global__ __launch_bounds__(256) void conv2_rest(
    const short* __restrict__ h1g, // [B,144,64] bf16
    const short* __restrict__ w2r, // [9][64][64] bf16
    const float* __restrict__ b2,  // [64]
    const float* __restrict__ w3,  // [10,64,4,4]
    const float* __restrict__ b3,  // [10]
    float* __restrict__ out)       // [B,10]
{
    // LDS: cbuf bf16 [64][101] = 12928B  (floats [0..3232))
    //      h2t fp32 [16][65]   = 4160B   (floats [3232..4272))
    //      prt overlays cbuf head after pool barrier.
    __shared__ float lds_f[4272];                // 17088 B -> 9 blocks LDS-wise
    short* cbuf = (short*)lds_f;
    float* h2t  = lds_f + 3232;
    float* prt  = lds_f;

    const int n_img = blockIdx.x;
    const int t = threadIdx.x;
    const int c = t >> 2;
    const int q = t & 3;
    const int wv = t >> 6, lane = t & 63;
    const int quad = lane >> 4, mrow = lane & 15;
    const short* h1 = h1g + (size_t)n_img * 9216;

    // ---- stage 2: conv2 as MFMA GEMM (M=64 cout, N=100 pad 112, K=576) ----
    // B-fragments direct from global h1 (L1-resident: 18KB/image).
    {
        int pos_b[7];
        #pragma unroll
        for (int nt = 0; nt < 7; ++nt) {
            int n = nt * 16 + mrow; if (n > 99) n = 99;   // clamp pad cols (discarded)
            int y = n / 10, xx = n - y * 10;
            pos_b[nt] = y * 12 + xx;
        }
        f32x4 acc[7];
        #pragma unroll
        for (int nt = 0; nt < 7; ++nt) acc[nt] = (f32x4){0.f, 0.f, 0.f, 0.f};

        #pragma unroll
        for (int ks = 0; ks < 18; ++ks) {
            const int s = ks >> 1, h = ks & 1;
            const int ky = s / 3, kx = s - ky * 3;
            const int koff = ky * 12 + kx;
            const int hoff = h * 32 + quad * 8;
            const short8 a = *(const short8*)(w2r + s * 4096 + (wv * 16 + mrow) * 64 + hoff);
            #pragma unroll
            for (int nt = 0; nt < 7; ++nt) {
                const short8 b = *(const short8*)(h1 + (pos_b[nt] + koff) * 64 + hoff);
                acc[nt] = __builtin_amdgcn_mfma_f32_16x16x32_bf16(a, b, acc[nt], 0, 0, 0);
            }
        }
        // epilogue: D[row=quad*4+r][col=mrow] -> cbuf[cout][pos] bf16, + bias
        #pragma unroll
        for (int nt = 0; nt < 7; ++nt) {
            const int n = nt * 16 + mrow;
            if (n < 100) {
                #pragma unroll
                for (int r = 0; r < 4; ++r) {
                    const int cout = wv * 16 + quad * 4 + r;
                    cbuf[cout * 101 + n] = f2bf(acc[nt][r] + b2[cout]);
                }
            }
        }
    }
    __syncthreads();

    // ---- stage 2b: pool 3x3 s2 + relu -> h2t[pos*65+cin] fp32 ----
    {
        const short* cb = cbuf + c * 101;
        #pragma unroll
        for (int k = 0; k < 4; ++k) {
            const int pos = q * 4 + k;
            const int py = pos >> 2, px = pos & 3;
            float m = -1e30f;
            #pragma unroll
            for (int a = 0; a < 3; ++a)
                #pragma unroll
                for (int b = 0; b < 3; ++b)
                    m = fmaxf(m, bf2f(cb[(2 * py + a) * 10 + (2 * px + b)]));
            h2t[pos * 65 + c] = fmaxf(m, 0.0f);
        }
    }
    __syncthreads();

    // ---- stage 3: conv3 4x4 -> out[n][10] ----
    if (t < 160) {
        const int o = t >> 4, l = t & 15;
        const float* w3o = w3 + o * 1024;
        float s = 0.0f;
        #pragma unroll
        for (int cc = 0; cc < 4; ++cc) {
            const int cin = l * 4 + cc;
            const float4 wv4a = *(const float4*)(w3o + cin * 16);
            const float4 wv4b = *(const float4*)(w3o + cin * 16 + 4);
            const float4 wv4c = *(const float4*)(w3o + cin * 16 + 8);
            const float4 wv4d = *(const float4*)(w3o + cin * 16 + 12);
            const float* hh = h2t + cin;           // h2t[k*65+cin]
            s += hh[0*65] * wv4a.x + hh[1*65] * wv4a.y + hh[2*65] * wv4a.z + hh[3*65] * wv4a.w;
            s += hh[4*65] * wv4b.x + hh[5*65] * wv4b.y + hh[6*65] * wv4b.z + hh[7*65] * wv4b.w;
            s += hh[8*65] * wv4c.x + hh[9*65] * wv4c.y + hh[10*65] * wv4c.z + hh[11*65] * wv4c.w;
            s += hh[12*65] * wv4d.x + hh[13*65] * wv4d.y + hh[14*65] * wv4d.z + hh[15*65] * wv4d.w;
        }
        prt[t] = s;   // cbuf dead (pool reads barriered above)
    }
    __syncthreads();
    if (t < 10) {
        float s = b3[t];
        #pragma unroll
        for (int l = 0; l < 16; ++l) s += prt[t * 16 + l];
        out[(size_t)n_img * 10 + t] = s;
    }
}

// ---------------- Fallback: exact R3 fused kernel (proven 52us) ----------------
__global__ __launch_bounds__(256) void convnet_fused(
    const float* __restrict__ x, const float* __restrict__ w1,
    const float* __restrict__ b1, const short* __restrict__ w2r,
    const float* __restrict__ b2, const float* __restrict__ w3,
    const float* __restrict__ b3, float* __restrict__ out)
{
    __shared__ float lds_f[7424];
    short* h1t  = (short*)lds_f;
    float* img  = lds_f + 5184;
    float* cbuf = lds_f;
    float* h2t  = lds_f + 6400;
    float* prt  = lds_f;

    const int n_img = blockIdx.x;
    const int t = threadIdx.x;
    const int c = t >> 2;
    const int q = t & 3;

    const float* img_g = x + (size_t)n_img * 784;
    for (int i = t; i < 784; i += 256) img[i] = img_g[i];
    __syncthreads();

    {
        const int oy = (q >> 1) * 6, ox = (q & 1) * 6;
        const int iy0 = 2 * oy, ix0 = 2 * ox;
        float w[9];
        #pragma unroll
        for (int k = 0; k < 9; ++k) w[k] = w1[c * 9 + k];
        const float bias = b1[c];
        float in0[15], in1[15], in2[15];
        #pragma unroll
        for (int s = 0; s < 15; ++s) in0[s] = img[(iy0 + 0) * 28 + ix0 + s];
        #pragma unroll
        for (int s = 0; s < 15; ++s) in1[s] = img[(iy0 + 1) * 28 + ix0 + s];
        float cm[3][6];
        #pragma unroll
        for (int r = 0; r < 13; ++r) {
            #pragma unroll
            for (int s = 0; s < 15; ++s) in2[s] = img[(iy0 + r + 2) * 28 + ix0 + s];
            #pragma unroll
            for (int px = 0; px < 6; ++px) cm[r % 3][px] = -1e30f;
            #pragma unroll
            for (int xx = 0; xx < 13; ++xx) {
                float a = bias;
                #pragma unroll
                for (int j = 0; j < 3; ++j) {
                    a += in0[xx + j] * w[j];
                    a += in1[xx + j] * w[3 + j];
                    a += in2[xx + j] * w[6 + j];
                }
                if ((xx & 1) == 0) {
                    if (xx >= 2 && xx <= 12) cm[r % 3][xx / 2 - 1] = fmaxf(cm[r % 3][xx / 2 - 1], a);
                    if (xx <= 10)            cm[r % 3][xx / 2]     = fmaxf(cm[r % 3][xx / 2], a);
                } else {
                    cm[r % 3][xx / 2] = fmaxf(cm[r % 3][xx / 2], a);
                }
            }
            if (r >= 2 && (r & 1) == 0) {
                const int py = r / 2 - 1;
                #pragma unroll
                for (int px = 0; px < 6; ++px) {
                    float m = fmaxf(fmaxf(cm[0][px], cm[1][px]), cm[2][px]);
                    h1t[((oy + py) * 12 + ox + px) * 72 + c] = f2bf(fmaxf(m, 0.0f));
                }
            }
            #pragma unroll
            for (int s = 0; s < 15; ++s) { in0[s] = in1[s]; in1[s] = in2[s]; }
        }
    }
    __syncthreads();

    const int wv = t >> 6, lane = t & 63;
    const int quad = lane >> 4, mrow = lane & 15;
    {
        int base_el[7];
        #pragma unroll
        for (int nt = 0; nt < 7; ++nt) {
            int n = nt * 16 + mrow; if (n > 99) n = 99;
            int y = n / 10, xx = n - y * 10;
            base_el[nt] = (y * 12 + xx) * 72;
        }
        f32x4 acc[7];
        #pragma unroll
        for (int nt = 0; nt < 7; ++nt) acc[nt] = (f32x4){0.f, 0.f, 0.f, 0.f};
        #pragma unroll
        for (int ks = 0; ks < 18; ++ks) {
            const int s = ks >> 1, h = ks & 1;
            const int ky = s / 3, kx = s - ky * 3;
            const short8 a = *(const short8*)(w2r + s * 4096 + (wv * 16 + mrow) * 64
                                              + h * 32 + quad * 8);
            #pragma unroll
            for (int nt = 0; nt < 7; ++nt) {
                const short8 b = *(const short8*)(h1t + base_el[nt]
                                                  + (ky * 12 + kx) * 72 + h * 32 + quad * 8);
                acc[nt] = __builtin_amdgcn_mfma_f32_16x16x32_bf16(a, b, acc[nt], 0, 0, 0);
            }
        }
        __syncthreads();
        #pragma unroll
        for (int nt = 0; nt < 7; ++nt) {
            const int n = nt * 16 + mrow;
            if (n < 100) {
                #pragma unroll
                for (int r = 0; r < 4; ++r) {
                    const int cout = wv * 16 + quad * 4 + r;
                    cbuf[cout * 100 + n] = acc[nt][r] + b2[cout];
                }
            }
        }
    }
    __syncthreads();
    {
        const float* cb = cbuf + c * 100;
        #pragma unroll
        for (int k = 0; k < 4; ++k) {
            const int pos = q * 4 + k;
            const int py = pos >> 2, px = pos & 3;
            float m = -1e30f;
            #pragma unroll
            for (int a = 0; a < 3; ++a)
                #pragma unroll
                for (int b = 0; b < 3; ++b)
                    m = fmaxf(m, cb[(2 * py + a) * 10 + (2 * px + b)]);
            h2t[pos * 64 + c] = fmaxf(m, 0.0f);
        }
    }
    __syncthreads();
    if (t < 160) {
        const int o = t >> 4, l = t & 15;
        const float* w3o = w3 + o * 1024;
        float s = 0.0f;
        #pragma unroll
        for (int cc = 0; cc < 4; ++cc) {
            const int cin = l * 4 + cc;
            const float4 wv4a = *(const float4*)(w3o + cin * 16);
            const float4 wv4b = *(const float4*)(w3o + cin * 16 + 4);
            const float4 wv4c = *(const float4*)(w3o + cin * 16 + 8);
            const float4 wv4d = *(const float4*)(w3o + cin * 16 + 12);
            const float* hh = h2t + cin;
            s += hh[0*64] * wv4a.x + hh[1*64] * wv4a.y + hh[2*64] * wv4a.z + hh[3*64] * wv4a.w;
            s += hh[4*64] * wv4b.x + hh[5*64] * wv4b.y + hh[6*64] * wv4b.z + hh[7*64] * wv4b.w;
            s += hh[8*64] * wv4c.x + hh[9*64] * wv4c.y + hh[10*64] * wv4c.z + hh[11*64] * wv4c.w;
            s += hh[12*64] * wv4d.x + hh[13*64] * wv4d.y + hh[14*64] * wv4d.z + hh[15*64] * wv4d.w;
        }
        prt[t] = s;
    }
    __syncthreads();
    if (t < 10) {
        float s = b3[t];
        #pragma unroll
        for (int l = 0; l < 16; ++l) s += prt[t * 16 + l];
        out[(size_t)n_img * 10 + t] = s;
    }
}

extern "C" void kernel_launch(void* const* d_in, const int* in_sizes, int n_in,
                              void* d_out, int out_size, void* d_ws, size_t ws_size,
                              hipStream_t stream) {
    const float* x  = (const float*)d_in[0];
    const float* w1 = (const float*)d_in[1];
    const float* b1 = (const float*)d_in[2];
    const float* w2 = (const float*)d_in[3];
    const float* b2 = (const float*)d_in[4];
    const float* w3 = (const float*)d_in[5];
    const float* b3 = (const float*)d_in[6];
    float* out = (float*)d_out;
    short* w2r = (short*)d_ws;            // 36864 bf16 = 73728 B

    const int B = in_sizes[0] / 784;      // 2048
    const size_t need = 73728u + (size_t)B * 9216u * 2u;   // w2r + h1g

    prep_w2<<<144, 256, 0, stream>>>(w2, w2r);
    if (ws_size >= need) {
        short* h1g = (short*)((char*)d_ws + 73728);
        conv1_pool<<<B, 256, 0, stream>>>(x, w1, b1, h1g);
        conv2_rest<<<B, 256, 0, stream>>>(h1g, w2r, b2, w3, b3, out);
    } else {
        convnet_fused<<<B, 256, 0, stream>>>(x, w1, b1, w2r, b2, w3, b3, out);
    }
}